// Round 5
// baseline (216.782 us; speedup 1.0000x reference)
//
#include <hip/hip_runtime.h>

// Problem constants (fixed): b=16, h=w=128, c=64, heads=4, head_dim=16
#define B_   16
#define C_   64
#define HH   128
#define WW   128
#define NN   16384
#define PADT 72    // phase1 transposed tiles pad (shorts)
#define PADB 72    // phase2 bf16 row pad (shorts)
#define PADO 66    // phase2 f32 out-staging pad

typedef short short8  __attribute__((ext_vector_type(8)));
typedef short short4v __attribute__((ext_vector_type(4)));
typedef float f32x4   __attribute__((ext_vector_type(4)));

__device__ __forceinline__ float act_elu1(float v) {
    return v > 0.f ? v + 1.f : __expf(v);   // elu(v)+1
}
__device__ __forceinline__ short f2bf(float f) {
    union { float f; unsigned u; } v; v.f = f;
    unsigned r = (v.u + 0x7FFFu + ((v.u >> 16) & 1u)) >> 16;  // RNE
    return (short)r;
}
__device__ __forceinline__ short8 pack8(float4 a, float4 b) {
    short8 r;
    r[0]=f2bf(a.x); r[1]=f2bf(a.y); r[2]=f2bf(a.z); r[3]=f2bf(a.w);
    r[4]=f2bf(b.x); r[5]=f2bf(b.y); r[6]=f2bf(b.z); r[7]=f2bf(b.w);
    return r;
}

// -log2(10000)/16
#define NEG_L2_10K_OVER16 (-0.8304820237218406f)

// ws layout (floats) — proven round-2 base layout + table appended:
//   [0, 1114112)           g_part[b*64+blk][1088]  (1024 kv + 64 km)
//   [1114112, 1130496)     g_kv[b][1024]
//   [1130496, 1131520)     g_km[b][64]
//   [1131520, 1135616)     rope table float2[coord(128)][t(16)] = (cos,sin)
#define WS_KV   1114112
#define WS_KM   1130496
#define WS_TBL  1131520

// ---------------------------------------------------------------------------
__global__ void init_kernel(float* __restrict__ ws) {
    int e = blockIdx.x * 256 + threadIdx.x;
    if (e < 2048) {
        int coord = e >> 4, t = e & 15;
        float theta = exp2f(NEG_L2_10K_OVER16 * (float)t);
        float s, c;
        sincosf((float)coord * theta, &s, &c);    // precise version
        ws[WS_TBL + 2*e]     = c;
        ws[WS_TBL + 2*e + 1] = s;
    }
}

// ---------------------------------------------------------------------------
// Phase 1 (v3 structure — partials proven bit-identical to round-2's):
// k = elu(x@Wk^T+b)+1 ; rope ; per-block partials of kv = k_rope^T v, km = sum(k)
// ---------------------------------------------------------------------------
__global__ __launch_bounds__(256) void la_phase1(
    const float* __restrict__ x, const float* __restrict__ qk_w,
    const float* __restrict__ qk_b, float* __restrict__ ws)
{
    __shared__ __align__(16) short sXT[64*PADT];  // x^T (v) [ch][p]
    __shared__ __align__(16) short sKT[64*PADT];  // roped k^T [ch][p]
    __shared__ float kmp[256];

    const int tid  = threadIdx.x;
    const int w    = tid >> 6;
    const int ln   = tid & 15;
    const int quad = (tid >> 4) & 3;
    const int b    = blockIdx.y;
    const float* xb = x + (size_t)b * (size_t)(NN * 64);
    const float2* tbl = (const float2*)(ws + WS_TBL);
    float* g_part = ws;

    // hoist Wk fragments into registers (rows 64..127 of qk_w)
    short8 wf[2][4];
    #pragma unroll
    for (int ks = 0; ks < 2; ++ks)
        #pragma unroll
        for (int nt = 0; nt < 4; ++nt) {
            const float* p = qk_w + (size_t)(64 + 16*nt + ln)*64 + 32*ks + 8*quad;
            wf[ks][nt] = pack8(*(const float4*)p, *(const float4*)(p+4));
        }
    float bias[4];
    #pragma unroll
    for (int nt = 0; nt < 4; ++nt) bias[nt] = qk_b[64 + 16*nt + ln];

    f32x4 acc2 = {0.f,0.f,0.f,0.f};
    float kmacc[4] = {0.f,0.f,0.f,0.f};

    const int sp = 4*(tid & 15);   // staging: position base
    const int sc = 4*(tid >> 4);   // staging: channel base

    for (int ck = 0; ck < 4; ++ck) {
        const int n0 = blockIdx.x*256 + ck*64;
        if (ck) __syncthreads();

        // stage x^T (register 4x4 transpose, vector b64 writes)
        {
            float4 r0 = *(const float4*)(xb + (size_t)(n0+sp+0)*64 + sc);
            float4 r1 = *(const float4*)(xb + (size_t)(n0+sp+1)*64 + sc);
            float4 r2 = *(const float4*)(xb + (size_t)(n0+sp+2)*64 + sc);
            float4 r3 = *(const float4*)(xb + (size_t)(n0+sp+3)*64 + sc);
            short4v t0 = { f2bf(r0.x), f2bf(r1.x), f2bf(r2.x), f2bf(r3.x) };
            short4v t1 = { f2bf(r0.y), f2bf(r1.y), f2bf(r2.y), f2bf(r3.y) };
            short4v t2 = { f2bf(r0.z), f2bf(r1.z), f2bf(r2.z), f2bf(r3.z) };
            short4v t3 = { f2bf(r0.w), f2bf(r1.w), f2bf(r2.w), f2bf(r3.w) };
            *(short4v*)(sXT + (sc+0)*PADT + sp) = t0;
            *(short4v*)(sXT + (sc+1)*PADT + sp) = t1;
            *(short4v*)(sXT + (sc+2)*PADT + sp) = t2;
            *(short4v*)(sXT + (sc+3)*PADT + sp) = t3;
        }

        // k-projection: A-frags straight from global (f32 -> bf16)
        f32x4 acc[4];
        #pragma unroll
        for (int nt = 0; nt < 4; ++nt) acc[nt] = (f32x4){0.f,0.f,0.f,0.f};
        #pragma unroll
        for (int ks = 0; ks < 2; ++ks) {
            const float* ap = xb + (size_t)(n0 + 16*w + ln)*64 + 32*ks + 8*quad;
            short8 a = pack8(*(const float4*)ap, *(const float4*)(ap+4));
            #pragma unroll
            for (int nt = 0; nt < 4; ++nt)
                acc[nt] = __builtin_amdgcn_mfma_f32_16x16x32_bf16(a, wf[ks][nt], acc[nt], 0, 0, 0);
        }

        // bias + elu + rope (table) ; write roped k^T ; accumulate km
        #pragma unroll
        for (int nt = 0; nt < 4; ++nt) {
            const int j  = 16*nt + ln;
            const int tq = (j >> 1) & 15;
            const bool isY = (j >> 1) < 16;
            const float sgn = (j & 1) ? 1.f : -1.f;
            #pragma unroll
            for (int r = 0; r < 4; ++r) {
                float kval = act_elu1(acc[nt][r] + bias[nt]);
                kmacc[nt] += kval;
                float P = __shfl_xor(kval, 1);
                int p_loc = 16*w + 4*quad + r;
                int n = n0 + p_loc;
                int coord = isY ? (n >> 7) : (n & 127);
                float2 cs = tbl[coord*16 + tq];
                float kr = kval*cs.x + sgn*P*cs.y;
                sKT[j*PADT + p_loc] = f2bf(kr);
            }
        }
        __syncthreads();

        // kv += k_rope^T v  (head = wave)
        #pragma unroll
        for (int ks = 0; ks < 2; ++ks) {
            short8 a  = *(const short8*)(sKT + (16*w + ln)*PADT + 32*ks + 8*quad);
            short8 bb = *(const short8*)(sXT + (16*w + ln)*PADT + 32*ks + 8*quad);
            acc2 = __builtin_amdgcn_mfma_f32_16x16x32_bf16(a, bb, acc2, 0, 0, 0);
        }
    }

    // deterministic per-block partial store: [b*64+blk][1088] = 1024 kv + 64 km
    float* pb = g_part + (size_t)(b*64 + blockIdx.x) * 1088;
    #pragma unroll
    for (int r = 0; r < 4; ++r)
        pb[w*256 + (4*quad + r)*16 + ln] = acc2[r];

    #pragma unroll
    for (int nt = 0; nt < 4; ++nt) {
        float v = kmacc[nt];
        v += __shfl_xor(v, 16);
        v += __shfl_xor(v, 32);
        if ((tid & 63) < 16) kmp[w*64 + 16*nt + ln] = v;
    }
    __syncthreads();
    if (tid < 64)
        pb[1024 + tid] = kmp[tid] + kmp[64 + tid] + kmp[128 + tid] + kmp[192 + tid];
}

// ---------------------------------------------------------------------------
// Reduce (round-2 verbatim): sum 64 per-block partials -> g_kv, g_km
// ---------------------------------------------------------------------------
__global__ __launch_bounds__(256) void la_reduce(
    const float* __restrict__ g_part, float* __restrict__ g_kv,
    float* __restrict__ g_km)
{
    int o = blockIdx.x * 256 + threadIdx.x;     // 0 .. 17407
    int b = o / 1088;
    int i = o - b * 1088;
    const float* p = g_part + (size_t)(b*64) * 1088 + i;
    float s = 0.f;
    #pragma unroll 8
    for (int nb = 0; nb < 64; ++nb) s += p[(size_t)nb * 1088];
    if (i < 1024) g_kv[b*1024 + i] = s;
    else          g_km[b*64 + (i - 1024)] = s;
}

// ---------------------------------------------------------------------------
// Phase 2 (round-2 verbatim — proven): q = elu(x@Wq^T+b)+1 ; z ;
// out = q_rope@kv*z + lepe. Block = 64 positions.
// ---------------------------------------------------------------------------
__global__ __launch_bounds__(256) void la_phase2(
    const float* __restrict__ x, const float* __restrict__ qk_w,
    const float* __restrict__ qk_b, const float* __restrict__ lepe_w,
    const float* __restrict__ lepe_b, const float* __restrict__ g_kv,
    const float* __restrict__ g_km, float* __restrict__ out)
{
    __shared__ __align__(16) char pool[32768];
    short* sX   = (short*)pool;              // [64][72] (aliased by sOut later)
    short* sW   = sX + 64*PADB;              // [64][72]
    float* sOut = (float*)pool;              // [64][66] f32, aliases sX+sW
    short* sQ   = (short*)(pool + 18432);    // [64][72] roped q row-major [p][ch]
    short* sKVB = sQ + 64*PADB;              // [64][40] head-padded kv^T (bf16)

    const int tid  = threadIdx.x;
    const int w    = tid >> 6;
    const int ln   = tid & 15;
    const int quad = (tid >> 4) & 3;
    const int b    = blockIdx.y;
    const int n0   = blockIdx.x * 64;
    const float* xb = x + (size_t)b * (size_t)(NN * C_);
    const float inv_n = 1.f / (float)NN;

    #pragma unroll
    for (int it = 0; it < 4; ++it) {
        int idx = tid + 256*it;
        int row = idx & 63, k4 = (idx >> 6) << 2;
        float4 xv = *(const float4*)(xb + (size_t)(n0 + row)*C_ + k4);
        short4v s4 = { f2bf(xv.x), f2bf(xv.y), f2bf(xv.z), f2bf(xv.w) };
        *(short4v*)(sX + row*PADB + k4) = s4;
        float4 wv = *(const float4*)(qk_w + row*64 + k4);   // Wq rows 0..63
        short4v s5 = { f2bf(wv.x), f2bf(wv.y), f2bf(wv.z), f2bf(wv.w) };
        *(short4v*)(sW + row*PADB + k4) = s5;
    }
    // kv (normalized) into B-operand layout, zero-padded to K=32 per head pair
    for (int idx = tid; idx < 1024; idx += 256) {
        int h = idx >> 8, d = (idx >> 4) & 15, e = idx & 15;
        float v = g_kv[b*1024 + idx] * inv_n;
        int rowb  = h*16 + e;
        int kpos  = (h & 1) ? 16 + d : d;
        int kzero = (h & 1) ? d : 16 + d;
        sKVB[rowb*40 + kpos]  = f2bf(v);
        sKVB[rowb*40 + kzero] = 0;
    }
    float biasq[4], kmv[4];
    #pragma unroll
    for (int nt = 0; nt < 4; ++nt) {
        biasq[nt] = qk_b[16*nt + ln];
        kmv[nt]   = g_km[b*64 + 16*nt + ln];
    }
    __syncthreads();

    // q-tile = X @ Wq^T via MFMA
    f32x4 acc[4];
    #pragma unroll
    for (int nt = 0; nt < 4; ++nt) acc[nt] = (f32x4){0.f,0.f,0.f,0.f};
    #pragma unroll
    for (int ks = 0; ks < 2; ++ks) {
        short8 a = *(const short8*)(sX + (16*w + ln)*PADB + 32*ks + 8*quad);
        #pragma unroll
        for (int nt = 0; nt < 4; ++nt) {
            short8 bf = *(const short8*)(sW + (16*nt + ln)*PADB + 32*ks + 8*quad);
            acc[nt] = __builtin_amdgcn_mfma_f32_16x16x32_bf16(a, bf, acc[nt], 0, 0, 0);
        }
    }

    // bias + elu + z + rope; write roped q row-major [p][ch]
    float z_all[4][4];
    #pragma unroll
    for (int nt = 0; nt < 4; ++nt) {
        const int j  = 16*nt + ln;
        const int t = j >> 1;
        const float theta = exp2f(NEG_L2_10K_OVER16 * (float)(t & 15));
        const bool isY = (t < 16);
        const float sgn = (j & 1) ? 1.f : -1.f;
        #pragma unroll
        for (int r = 0; r < 4; ++r) {
            float qval = act_elu1(acc[nt][r] + biasq[nt]);
            float dotp = qval * kmv[nt];
            dotp += __shfl_xor(dotp, 1);
            dotp += __shfl_xor(dotp, 2);
            dotp += __shfl_xor(dotp, 4);
            dotp += __shfl_xor(dotp, 8);
            z_all[nt][r] = 1.f / (dotp * inv_n + 1e-6f);
            float P = __shfl_xor(qval, 1);
            int p_loc = 16*w + 4*quad + r;
            int n = n0 + p_loc;
            float coord = isY ? (float)(n >> 7) : (float)(n & 127);
            float s, c;
            __sincosf(coord * theta, &s, &c);
            float qr = qval*c + sgn*P*s;
            sQ[p_loc*PADB + j] = f2bf(qr);
        }
    }
    __syncthreads();   // sQ + sKVB ready

    // attn: out = q_rope @ kv_n, M-tile w, all 4 heads (K=32, half-padded)
    f32x4 accq[4];
    #pragma unroll
    for (int h = 0; h < 4; ++h) accq[h] = (f32x4){0.f,0.f,0.f,0.f};
    #pragma unroll
    for (int P2 = 0; P2 < 2; ++P2) {
        short8 a = *(const short8*)(sQ + (16*w + ln)*PADB + 32*P2 + 8*quad);
        #pragma unroll
        for (int hh = 0; hh < 2; ++hh) {
            int h = 2*P2 + hh;
            short8 bf = *(const short8*)(sKVB + (h*16 + ln)*40 + 8*quad);
            accq[h] = __builtin_amdgcn_mfma_f32_16x16x32_bf16(a, bf, accq[h], 0, 0, 0);
        }
    }
    __syncthreads();   // everyone done reading sQ/sX/sW -> safe to alias sOut

    // stage attn*z as f32, channel-major [ch][p]
    #pragma unroll
    for (int h = 0; h < 4; ++h)
        #pragma unroll
        for (int r = 0; r < 4; ++r)
            sOut[(16*h + ln)*PADO + 16*w + 4*quad + r] = accq[h][r] * z_all[h][r];
    __syncthreads();

    // lepe 3x3 depthwise conv (register sliding window) + combine + store
    const int ch = tid >> 2, sub = tid & 3, p0 = 16*sub;
    const int yy = n0 >> 7, xbase = n0 & 127, gx0 = xbase + p0;
    float wv9[9];
    #pragma unroll
    for (int tap = 0; tap < 9; ++tap) wv9[tap] = lepe_w[ch*9 + tap];
    const float lb = lepe_b[ch];
    float accl[16];
    #pragma unroll
    for (int j = 0; j < 16; ++j) accl[j] = 0.f;
    #pragma unroll
    for (int dy = -1; dy <= 1; ++dy) {
        int y2 = yy + dy;
        if ((unsigned)y2 >= HH) continue;
        const float* rp = xb + (size_t)(y2*WW)*C_ + ch;
        float cb[18];
        #pragma unroll
        for (int jj = 0; jj < 18; ++jj) {
            int col = gx0 - 1 + jj;
            cb[jj] = ((unsigned)col < WW) ? rp[(size_t)col*C_] : 0.f;
        }
        float w0 = wv9[(dy+1)*3 + 0], w1 = wv9[(dy+1)*3 + 1], w2 = wv9[(dy+1)*3 + 2];
        #pragma unroll
        for (int j = 0; j < 16; ++j)
            accl[j] += cb[j]*w0 + cb[j+1]*w1 + cb[j+2]*w2;
    }
    float* outp = out + ((size_t)(b*64 + ch))*NN + n0 + p0;
    #pragma unroll
    for (int g = 0; g < 4; ++g) {
        float2 a0 = *(const float2*)(sOut + ch*PADO + p0 + 4*g);
        float2 a1 = *(const float2*)(sOut + ch*PADO + p0 + 4*g + 2);
        float4 o4 = { a0.x + accl[4*g+0] + lb, a0.y + accl[4*g+1] + lb,
                      a1.x + accl[4*g+2] + lb, a1.y + accl[4*g+3] + lb };
        *(float4*)(outp + 4*g) = o4;
    }
}

extern "C" void kernel_launch(void* const* d_in, const int* in_sizes, int n_in,
                              void* d_out, int out_size, void* d_ws, size_t ws_size,
                              hipStream_t stream) {
    const float* x      = (const float*)d_in[0];
    const float* qk_w   = (const float*)d_in[3];
    const float* qk_b   = (const float*)d_in[4];
    const float* lepe_w = (const float*)d_in[5];
    const float* lepe_b = (const float*)d_in[6];
    float* out = (float*)d_out;
    float* ws  = (float*)d_ws;

    float* g_part = ws;                 // [0, 1114112)
    float* g_kv   = ws + WS_KV;         // [1114112, 1130496)
    float* g_km   = ws + WS_KM;         // [1130496, 1131520)

    hipLaunchKernelGGL(init_kernel, dim3(8), dim3(256), 0, stream, ws);
    hipLaunchKernelGGL(la_phase1, dim3(64, B_), dim3(256), 0, stream, x, qk_w, qk_b, ws);
    hipLaunchKernelGGL(la_reduce, dim3(68), dim3(256), 0, stream, g_part, g_kv, g_km);
    hipLaunchKernelGGL(la_phase2, dim3(256, B_), dim3(256), 0, stream,
                       x, qk_w, qk_b, lepe_w, lepe_b, g_kv, g_km, out);
}